// Round 4
// baseline (163.533 us; speedup 1.0000x reference)
//
#include <hip/hip_runtime.h>
#include <math.h>

#define Wd 320
#define Hd 256
#define Bd 8
#define Cd 3
#define Dd 64
#define HWd (Hd * Wd)          // 81920
#define PLW (HWd / 2)          // 40960 words per copy
#define PLB (HWd * 2)          // 163840 bytes per copy
#define DT 8                   // d-chunk per thread

typedef _Float16 half2_t __attribute__((ext_vector_type(2)));

#if __has_builtin(__builtin_amdgcn_fdot2)
#define FDOT2(a, b, c) __builtin_amdgcn_fdot2((a), (b), (c), false)
#else
static __device__ __forceinline__ float FDOT2(half2_t a, half2_t b, float c) {
    return (float)a.x * (float)b.x + (float)a.y * (float)b.y + c;
}
#endif

// pack two floats into one dword of 2 f16 (RTZ, single v_cvt_pkrtz)
static __device__ __forceinline__ half2_t pkrtz(float a, float b) {
    return __builtin_bit_cast(half2_t, __builtin_amdgcn_cvt_pkrtz(a, b));
}

// ---- pack: right [b][c][HW] f32 -> per plane: A-words (pix 2w,2w+1) then
//      B-words (pix 2w+1, 2w+2), f16. Dual copy makes any x-pair a 4B-aligned dword.
__global__ __launch_bounds__(256) void pack_right(const float* __restrict__ right,
                                                  unsigned* __restrict__ wsu) {
    const int wi = blockIdx.x * 256 + threadIdx.x;   // [0, PLW)
    const int plane = blockIdx.y;                    // [0, 24) == b*3+c
    const float* src = right + (size_t)plane * HWd;
    const int p0 = 2 * wi;
    const float f0 = src[p0];
    const float f1 = src[p0 + 1];
    const float f2 = (p0 + 2 < HWd) ? src[p0 + 2] : f1;
    const half2_t A  = pkrtz(f0, f1);
    const half2_t B2 = pkrtz(f1, f2);
    unsigned* dst = wsu + (size_t)plane * (2 * PLW);
    dst[wi] = __builtin_bit_cast(unsigned, A);
    dst[PLW + wi] = __builtin_bit_cast(unsigned, B2);
}

// ---- main: thread = one pixel q, loops DT depths and 8 batches x 3 channels.
__global__ __launch_bounds__(256) void costvol_kernel(
    const float* __restrict__ left,     // [B,3,H,W] f32
    const unsigned* __restrict__ wsu,   // packed f16 planes (dual copy)
    float* __restrict__ out,            // [B,D,H,W] f32
    double a00, double a01, double a02,
    double a10, double a11, double a12,
    double a20, double a21, double a22,
    float kt0, float kt1, float kt2)
{
    const int q = blockIdx.x * 256 + threadIdx.x;   // pixel id in [0, H*W)
    const int d0 = blockIdx.y * DT;
    const int x = q % Wd;
    const int y = q / Wd;

    // hoisted: K*R*K^-1 row applied to [x,y,1] in f64 (matches reference exactly)
    const float k0 = (float)(a00 * (double)x + a01 * (double)y + a02);
    const float k1 = (float)(a10 * (double)x + a11 * (double)y + a12);
    const float k2 = (float)(a20 * (double)x + a21 * (double)y + a22);

    // hoisted: all 24 left values for this pixel
    float lf[Bd][Cd];
#pragma unroll
    for (int b = 0; b < Bd; ++b)
#pragma unroll
        for (int c = 0; c < Cd; ++c)
            lf[b][c] = left[(size_t)(b * Cd + c) * HWd + q];

    const float base  = (float)(1.0 / 50.0);
    const float stepf = (float)((1.0 / 0.5 - 1.0 / 50.0) / 63.0);

#pragma unroll 1
    for (int dd = 0; dd < DT; ++dd) {
        const int d = d0 + dd;
        const float depth = 1.0f / (base + (float)d * stepf);

        const float tx = k0 * depth + kt0;
        const float ty = k1 * depth + kt1;
        const float tz = k2 * depth + kt2;
        const float r = __builtin_amdgcn_rcpf(tz + 1e-6f);
        // folded: ix = ((u - W/2)/(W/2) + 1) * 0.5 * (W-1)  ==  u * (W-1)/W
        const float ix = (tx * r) * (159.5f / 160.0f);
        const float iy = (ty * r) * (127.5f / 128.0f);

        // ---- x axis: weights in the fetched-pixel basis, base xb = clamp(x0,0,W-2)
        const float x0f = floorf(ix);
        const float wx1 = ix - x0f;
        const float wx0 = 1.0f - wx1;
        const bool gex = (x0f >= 0.0f);
        const bool lex = (x0f <= (float)(Wd - 2));
        const float a0x = gex ? (lex ? wx0 : 0.0f)
                              : ((x0f == -1.0f) ? wx1 : 0.0f);
        const float a1x = gex ? (lex ? wx1 : ((x0f == (float)(Wd - 1)) ? wx0 : 0.0f))
                              : 0.0f;
        const float xbf = fminf(fmaxf(x0f, 0.0f), (float)(Wd - 2));

        // ---- y axis
        const float y0f = floorf(iy);
        const float wy1 = iy - y0f;
        const float wy0 = 1.0f - wy1;
        const bool gey = (y0f >= 0.0f);
        const bool ley = (y0f <= (float)(Hd - 2));
        const float a0y = gey ? (ley ? wy0 : 0.0f)
                              : ((y0f == -1.0f) ? wy1 : 0.0f);
        const float a1y = gey ? (ley ? wy1 : ((y0f == (float)(Hd - 1)) ? wy0 : 0.0f))
                              : 0.0f;
        const float ybf = fminf(fmaxf(y0f, 0.0f), (float)(Hd - 2));

        // 2x2 weights -> two f16 pairs (one cvt_pkrtz each)
        const half2_t wtop = pkrtz(a0x * a0y, a1x * a0y);
        const half2_t wbot = pkrtz(a0x * a1y, a1x * a1y);

        // dword offset: even ibase -> copy A at ibase*2 B; odd -> copy B at +PLB-2
        const int xb = (int)xbf;
        const int yb = (int)ybf;
        const int ibase = yb * Wd + xb;
        const int e = ibase & 1;
        const unsigned w0 = ((unsigned)(ibase * 2) + (unsigned)e * (unsigned)(PLB - 2)) >> 2;

#pragma unroll
        for (int b = 0; b < Bd; ++b) {
            float acc = 0.0f;
#pragma unroll
            for (int c = 0; c < Cd; ++c) {
                const unsigned* pl = wsu + (size_t)(b * Cd + c) * (2 * PLW); // uniform -> SGPR base
                const unsigned ut = pl[w0];          // top row pair (xb, xb+1)
                const unsigned ub = pl[w0 + Wd / 2]; // bottom row: +640 bytes (imm offset)
                const half2_t st = __builtin_bit_cast(half2_t, ut);
                const half2_t sb = __builtin_bit_cast(half2_t, ub);
                const float wrp = FDOT2(wtop, st, FDOT2(wbot, sb, 0.0f));
                acc += fabsf(wrp - lf[b][c]);
            }
            out[(size_t)(b * Dd + d) * HWd + q] = acc;
        }
    }
}

// ---------------- host-side geometry (pure f64, deterministic) ----------------

static void invert4(const double A[4][4], double inv[4][4]) {
    double M[4][8];
    for (int i = 0; i < 4; ++i) {
        for (int j = 0; j < 4; ++j) { M[i][j] = A[i][j]; M[i][j + 4] = (i == j) ? 1.0 : 0.0; }
    }
    for (int col = 0; col < 4; ++col) {
        int piv = col;
        for (int r = col + 1; r < 4; ++r)
            if (fabs(M[r][col]) > fabs(M[piv][col])) piv = r;
        if (piv != col)
            for (int j = 0; j < 8; ++j) { double t = M[col][j]; M[col][j] = M[piv][j]; M[piv][j] = t; }
        const double p = M[col][col];
        for (int j = 0; j < 8; ++j) M[col][j] /= p;
        for (int r = 0; r < 4; ++r) if (r != col) {
            const double f = M[r][col];
            for (int j = 0; j < 8; ++j) M[r][j] -= f * M[col][j];
        }
    }
    for (int i = 0; i < 4; ++i)
        for (int j = 0; j < 4; ++j) inv[i][j] = M[i][j + 4];
}

static void mul4(const double A[4][4], const double B[4][4], double C[4][4]) {
    for (int i = 0; i < 4; ++i)
        for (int j = 0; j < 4; ++j) {
            double s = 0.0;
            for (int k = 0; k < 4; ++k) s += A[i][k] * B[k][j];
            C[i][j] = s;
        }
}

static void mul3(const double A[3][3], const double B[3][3], double C[3][3]) {
    for (int i = 0; i < 3; ++i)
        for (int j = 0; j < 3; ++j) {
            double s = 0.0;
            for (int k = 0; k < 3; ++k) s += A[i][k] * B[k][j];
            C[i][j] = s;
        }
}

extern "C" void kernel_launch(void* const* d_in, const int* in_sizes, int n_in,
                              void* d_out, int out_size, void* d_ws, size_t ws_size,
                              hipStream_t stream) {
    const float* left  = (const float*)d_in[0];
    const float* right = (const float*)d_in[1];
    float* out = (float*)d_out;
    unsigned* wsu = (unsigned*)d_ws;   // needs 24 * HW * 4 B = 7.9 MB

    const double LP[4][4] = {
        {0.07543147, 0.61393189, -0.78574661, 1.3405},
        {0.9970987, -0.03837025, 0.06574118, 0.6266},
        {0.01021131, -0.78842588, -0.61504501, 1.6575},
        {0.0, 0.0, 0.0, 1.0}};
    const double RP[4][4] = {
        {0.0640527011, 0.640832173, -0.765004168, 1.316},
        {0.997946496, -0.0409736058, 0.0492336713, 0.6254},
        {0.000205541383, -0.766586779, -0.642140692, 1.6196},
        {0.0, 0.0, 0.0, 1.0}};
    double K[3][3] = {{525.0, 0.0, 319.5}, {0.0, 525.0, 239.5}, {0.0, 0.0, 1.0}};
    for (int j = 0; j < 3; ++j) K[0][j] *= (double)Wd / 640.0;
    for (int j = 0; j < 3; ++j) K[1][j] *= (double)Hd / 480.0;

    double iRP[4][4];
    invert4(RP, iRP);
    double l2r[4][4];
    mul4(iRP, LP, l2r);

    double Rm[3][3], t[3];
    for (int i = 0; i < 3; ++i) {
        for (int j = 0; j < 3; ++j) Rm[i][j] = l2r[i][j];
        t[i] = l2r[i][3];
    }

    const double iK[3][3] = {
        {1.0 / K[0][0], 0.0, -K[0][2] / K[0][0]},
        {0.0, 1.0 / K[1][1], -K[1][2] / K[1][1]},
        {0.0, 0.0, 1.0}};

    double T1[3][3], KRKi[3][3];
    mul3(K, Rm, T1);
    mul3(T1, iK, KRKi);

    double Ktd[3] = {0.0, 0.0, 0.0};
    for (int i = 0; i < 3; ++i)
        for (int k = 0; k < 3; ++k) Ktd[i] += K[i][k] * t[k];
    const float kt0 = (float)Ktd[0], kt1 = (float)Ktd[1], kt2 = (float)Ktd[2];

    // 1) pack right -> dual-copy f16 planes
    {
        dim3 grid(PLW / 256, Bd * Cd, 1);   // 160 x 24
        pack_right<<<grid, dim3(256), 0, stream>>>(right, wsu);
    }

    // 2) cost volume
    {
        dim3 grid(HWd / 256, Dd / DT, 1);   // 320 x 8
        costvol_kernel<<<grid, dim3(256), 0, stream>>>(
            left, wsu, out,
            KRKi[0][0], KRKi[0][1], KRKi[0][2],
            KRKi[1][0], KRKi[1][1], KRKi[1][2],
            KRKi[2][0], KRKi[2][1], KRKi[2][2],
            kt0, kt1, kt2);
    }
}

// Round 5
// 60.467 us; speedup vs baseline: 2.7045x; 2.7045x over previous
//
#include <hip/hip_runtime.h>
#include <hip/hip_fp16.h>
#include <math.h>

#define Wd 320
#define Hd 256
#define Bd 8
#define Cd 3
#define Dd 64
#define HWd (Hd * Wd)   // 81920

// ws layout: uint4 rpack[3][HW] (right), then uint4 lpack[3][HW] (left).
// Each uint4 = 8 f16 = batches 0..7 of one (c, pixel). Total 7.86 MB.

// ---- pack: [B][C][HW] f32 -> [C][HW] x (8 f16, batch-innermost), RNE ----
__global__ __launch_bounds__(256) void pack_f16(const float* __restrict__ right,
                                                const float* __restrict__ left,
                                                uint4* __restrict__ ws) {
    const int p = blockIdx.x * 256 + threadIdx.x;   // pixel in [0, HW)
    const int plane = blockIdx.y;                   // 0..5: 0-2 right c, 3-5 left c
    const int c = plane % Cd;
    const float* src = (plane < Cd ? right : left) + (size_t)c * HWd + p;
    unsigned w[4];
#pragma unroll
    for (int k = 0; k < 4; ++k) {
        const float f0 = src[(size_t)(2 * k) * (Cd * HWd)];
        const float f1 = src[(size_t)(2 * k + 1) * (Cd * HWd)];
        const __half2 h = __halves2half2(__float2half_rn(f0), __float2half_rn(f1));
        w[k] = __builtin_bit_cast(unsigned, h);
    }
    ws[(size_t)plane * HWd + p] = make_uint4(w[0], w[1], w[2], w[3]);
}

// ---- main: thread = (d, pixel); 12 uint4 gathers; packed-f16 math over 8 batches ----
__global__ __launch_bounds__(256) void costvol_kernel(
    const uint4* __restrict__ ws,     // rpack then lpack
    float* __restrict__ out,          // [B,D,H,W] f32
    double a00, double a01, double a02,
    double a10, double a11, double a12,
    double a20, double a21, double a22,
    float kt0, float kt1, float kt2)
{
    const int q = blockIdx.x * 256 + threadIdx.x;  // pixel id in [0, H*W)
    const int d = blockIdx.y;
    const int x = q % Wd;
    const int y = q / Wd;

    // ---- coordinate math: verbatim from the round-2 passing kernel ----
    const float base  = (float)(1.0 / 50.0);
    const float stepf = (float)((1.0 / 0.5 - 1.0 / 50.0) / 63.0);
    const float depth = 1.0f / (base + (float)d * stepf);

    const float k0 = (float)(a00 * (double)x + a01 * (double)y + a02);
    const float k1 = (float)(a10 * (double)x + a11 * (double)y + a12);
    const float k2 = (float)(a20 * (double)x + a21 * (double)y + a22);

    const float tx = k0 * depth + kt0;
    const float ty = k1 * depth + kt1;
    const float tz = k2 * depth + kt2;

    const float den = tz + 1e-6f;
    const float u = tx / den;
    const float v = ty / den;

    const float gx = (u - (float)(Wd / 2)) / (float)(Wd / 2);
    const float gy = (v - (float)(Hd / 2)) / (float)(Hd / 2);
    const float ix = (gx + 1.0f) * 0.5f * (float)(Wd - 1);
    const float iy = (gy + 1.0f) * 0.5f * (float)(Hd - 1);

    const float x0f = floorf(ix);
    const float y0f = floorf(iy);
    const float wx1 = ix - x0f;
    const float wy1 = iy - y0f;
    const float wx0 = 1.0f - wx1;
    const float wy0 = 1.0f - wy1;
    const float x1f = x0f + 1.0f;
    const float y1f = y0f + 1.0f;

    const float vx0 = (x0f >= 0.0f && x0f <= (float)(Wd - 1)) ? 1.0f : 0.0f;
    const float vx1 = (x1f >= 0.0f && x1f <= (float)(Wd - 1)) ? 1.0f : 0.0f;
    const float vy0 = (y0f >= 0.0f && y0f <= (float)(Hd - 1)) ? 1.0f : 0.0f;
    const float vy1 = (y1f >= 0.0f && y1f <= (float)(Hd - 1)) ? 1.0f : 0.0f;

    const float w00 = wx0 * wy0 * (vx0 * vy0);
    const float w10 = wx1 * wy0 * (vx1 * vy0);
    const float w01 = wx0 * wy1 * (vx0 * vy1);
    const float w11 = wx1 * wy1 * (vx1 * vy1);

    const int xi0 = (int)fminf(fmaxf(x0f, 0.0f), (float)(Wd - 1));
    const int xi1 = (int)fminf(fmaxf(x1f, 0.0f), (float)(Wd - 1));
    const int yi0 = (int)fminf(fmaxf(y0f, 0.0f), (float)(Hd - 1));
    const int yi1 = (int)fminf(fmaxf(y1f, 0.0f), (float)(Hd - 1));

    const int i00 = yi0 * Wd + xi0;
    const int i10 = yi0 * Wd + xi1;
    const int i01 = yi1 * Wd + xi0;
    const int i11 = yi1 * Wd + xi1;

    // weights as duplicated f16 pairs
    const __half2 w00p = __half2half2(__float2half_rn(w00));
    const __half2 w10p = __half2half2(__float2half_rn(w10));
    const __half2 w01p = __half2half2(__float2half_rn(w01));
    const __half2 w11p = __half2half2(__float2half_rn(w11));

    // packed f16 accumulators: acc[k] holds batches (2k, 2k+1)
    __half2 acc[4];
#pragma unroll
    for (int k = 0; k < 4; ++k) acc[k] = __half2half2(__float2half_rn(0.0f));

#pragma unroll
    for (int c = 0; c < Cd; ++c) {
        const uint4* rc = ws + (size_t)c * HWd;          // SGPR base
        const uint4 g00 = rc[i00];
        const uint4 g10 = rc[i10];
        const uint4 g01 = rc[i01];
        const uint4 g11 = rc[i11];
        const uint4 lv = ws[(size_t)(Cd + c) * HWd + q]; // packed left, coalesced

        const unsigned* u00 = (const unsigned*)&g00;
        const unsigned* u10 = (const unsigned*)&g10;
        const unsigned* u01 = (const unsigned*)&g01;
        const unsigned* u11 = (const unsigned*)&g11;
        const unsigned* ul  = (const unsigned*)&lv;

#pragma unroll
        for (int k = 0; k < 4; ++k) {
            const __half2 h00 = __builtin_bit_cast(__half2, u00[k]);
            const __half2 h10 = __builtin_bit_cast(__half2, u10[k]);
            const __half2 h01 = __builtin_bit_cast(__half2, u01[k]);
            const __half2 h11 = __builtin_bit_cast(__half2, u11[k]);
            const __half2 hl  = __builtin_bit_cast(__half2, ul[k]);
            __half2 wrp = __hfma2(w00p, h00,
                          __hfma2(w10p, h10,
                          __hfma2(w01p, h01,
                          __hmul2(w11p, h11))));
            const __half2 df = __habs2(__hsub2(wrp, hl));
            acc[k] = __hadd2(acc[k], df);
        }
    }

    const int out_off = d * HWd + q;
#pragma unroll
    for (int k = 0; k < 4; ++k) {
        const float lo = __low2float(acc[k]);
        const float hi = __high2float(acc[k]);
        out[(size_t)(2 * k) * (Dd * HWd) + out_off] = lo;
        out[(size_t)(2 * k + 1) * (Dd * HWd) + out_off] = hi;
    }
}

// ---------------- host-side geometry (pure f64, deterministic) ----------------

static void invert4(const double A[4][4], double inv[4][4]) {
    double M[4][8];
    for (int i = 0; i < 4; ++i) {
        for (int j = 0; j < 4; ++j) { M[i][j] = A[i][j]; M[i][j + 4] = (i == j) ? 1.0 : 0.0; }
    }
    for (int col = 0; col < 4; ++col) {
        int piv = col;
        for (int r = col + 1; r < 4; ++r)
            if (fabs(M[r][col]) > fabs(M[piv][col])) piv = r;
        if (piv != col)
            for (int j = 0; j < 8; ++j) { double t = M[col][j]; M[col][j] = M[piv][j]; M[piv][j] = t; }
        const double p = M[col][col];
        for (int j = 0; j < 8; ++j) M[col][j] /= p;
        for (int r = 0; r < 4; ++r) if (r != col) {
            const double f = M[r][col];
            for (int j = 0; j < 8; ++j) M[r][j] -= f * M[col][j];
        }
    }
    for (int i = 0; i < 4; ++i)
        for (int j = 0; j < 4; ++j) inv[i][j] = M[i][j + 4];
}

static void mul4(const double A[4][4], const double B[4][4], double C[4][4]) {
    for (int i = 0; i < 4; ++i)
        for (int j = 0; j < 4; ++j) {
            double s = 0.0;
            for (int k = 0; k < 4; ++k) s += A[i][k] * B[k][j];
            C[i][j] = s;
        }
}

static void mul3(const double A[3][3], const double B[3][3], double C[3][3]) {
    for (int i = 0; i < 3; ++i)
        for (int j = 0; j < 3; ++j) {
            double s = 0.0;
            for (int k = 0; k < 3; ++k) s += A[i][k] * B[k][j];
            C[i][j] = s;
        }
}

extern "C" void kernel_launch(void* const* d_in, const int* in_sizes, int n_in,
                              void* d_out, int out_size, void* d_ws, size_t ws_size,
                              hipStream_t stream) {
    const float* left  = (const float*)d_in[0];
    const float* right = (const float*)d_in[1];
    float* out = (float*)d_out;
    uint4* ws = (uint4*)d_ws;   // needs 6 * HW * 16 B = 7.86 MB

    const double LP[4][4] = {
        {0.07543147, 0.61393189, -0.78574661, 1.3405},
        {0.9970987, -0.03837025, 0.06574118, 0.6266},
        {0.01021131, -0.78842588, -0.61504501, 1.6575},
        {0.0, 0.0, 0.0, 1.0}};
    const double RP[4][4] = {
        {0.0640527011, 0.640832173, -0.765004168, 1.316},
        {0.997946496, -0.0409736058, 0.0492336713, 0.6254},
        {0.000205541383, -0.766586779, -0.642140692, 1.6196},
        {0.0, 0.0, 0.0, 1.0}};
    double K[3][3] = {{525.0, 0.0, 319.5}, {0.0, 525.0, 239.5}, {0.0, 0.0, 1.0}};
    for (int j = 0; j < 3; ++j) K[0][j] *= (double)Wd / 640.0;
    for (int j = 0; j < 3; ++j) K[1][j] *= (double)Hd / 480.0;

    double iRP[4][4];
    invert4(RP, iRP);
    double l2r[4][4];
    mul4(iRP, LP, l2r);

    double Rm[3][3], t[3];
    for (int i = 0; i < 3; ++i) {
        for (int j = 0; j < 3; ++j) Rm[i][j] = l2r[i][j];
        t[i] = l2r[i][3];
    }

    const double iK[3][3] = {
        {1.0 / K[0][0], 0.0, -K[0][2] / K[0][0]},
        {0.0, 1.0 / K[1][1], -K[1][2] / K[1][1]},
        {0.0, 0.0, 1.0}};

    double T1[3][3], KRKi[3][3];
    mul3(K, Rm, T1);
    mul3(T1, iK, KRKi);

    double Ktd[3] = {0.0, 0.0, 0.0};
    for (int i = 0; i < 3; ++i)
        for (int k = 0; k < 3; ++k) Ktd[i] += K[i][k] * t[k];
    const float kt0 = (float)Ktd[0], kt1 = (float)Ktd[1], kt2 = (float)Ktd[2];

    // 1) pack right + left -> [C][HW] x 8 f16 (batch-innermost)
    {
        dim3 grid(HWd / 256, 2 * Cd, 1);   // 320 x 6
        pack_f16<<<grid, dim3(256), 0, stream>>>(right, left, ws);
    }

    // 2) cost volume
    {
        dim3 grid(HWd / 256, Dd, 1);   // 320 x 64
        costvol_kernel<<<grid, dim3(256), 0, stream>>>(
            ws, out,
            KRKi[0][0], KRKi[0][1], KRKi[0][2],
            KRKi[1][0], KRKi[1][1], KRKi[1][2],
            KRKi[2][0], KRKi[2][1], KRKi[2][2],
            kt0, kt1, kt2);
    }
}

// Round 6
// 56.813 us; speedup vs baseline: 2.8785x; 1.0643x over previous
//
#include <hip/hip_runtime.h>
#include <hip/hip_fp16.h>
#include <math.h>

#define Wd 320
#define Hd 256
#define Bd 8
#define Cd 3
#define Dd 64
#define HWd (Hd * Wd)   // 81920
#define DT 2            // depths per thread

// ws layout: uint4 rpack[3][HW] (right), then uint4 lpack[3][HW] (left).
// Each uint4 = 8 f16 = batches 0..7 of one (c, pixel). Total 7.86 MB -> L2-resident.

// ---- pack: [B][C][HW] f32 -> [C][HW] x (8 f16, batch-innermost), RNE ----
__global__ __launch_bounds__(256) void pack_f16(const float* __restrict__ right,
                                                const float* __restrict__ left,
                                                uint4* __restrict__ ws) {
    const int p = blockIdx.x * 256 + threadIdx.x;   // pixel in [0, HW)
    const int plane = blockIdx.y;                   // 0..5: 0-2 right c, 3-5 left c
    const int c = plane % Cd;
    const float* src = (plane < Cd ? right : left) + (size_t)c * HWd + p;
    unsigned w[4];
#pragma unroll
    for (int k = 0; k < 4; ++k) {
        const float f0 = src[(size_t)(2 * k) * (Cd * HWd)];
        const float f1 = src[(size_t)(2 * k + 1) * (Cd * HWd)];
        const __half2 h = __halves2half2(__float2half_rn(f0), __float2half_rn(f1));
        w[k] = __builtin_bit_cast(unsigned, h);
    }
    ws[(size_t)plane * HWd + p] = make_uint4(w[0], w[1], w[2], w[3]);
}

// ---- main: thread = (pixel, 2 depths); 12 uint4 gathers per d; packed-f16 math ----
__global__ __launch_bounds__(256) void costvol_kernel(
    const uint4* __restrict__ ws,     // rpack then lpack
    float* __restrict__ out,          // [B,D,H,W] f32
    double a00, double a01, double a02,
    double a10, double a11, double a12,
    double a20, double a21, double a22,
    float kt0, float kt1, float kt2)
{
    const int q = blockIdx.x * 256 + threadIdx.x;  // pixel id in [0, H*W)
    const int d0 = blockIdx.y * DT;
    const int x = q % Wd;
    const int y = q / Wd;

    // hoisted across depths: f64 KRKi row (matches reference exactly)
    const float k0 = (float)(a00 * (double)x + a01 * (double)y + a02);
    const float k1 = (float)(a10 * (double)x + a11 * (double)y + a12);
    const float k2 = (float)(a20 * (double)x + a21 * (double)y + a22);

    // hoisted: packed left for this pixel (3 coalesced uint4 = 24 f16)
    uint4 lv[Cd];
#pragma unroll
    for (int c = 0; c < Cd; ++c) lv[c] = ws[(size_t)(Cd + c) * HWd + q];

    const float base  = (float)(1.0 / 50.0);
    const float stepf = (float)((1.0 / 0.5 - 1.0 / 50.0) / 63.0);

#pragma unroll
    for (int dd = 0; dd < DT; ++dd) {
        const int d = d0 + dd;

        // ---- coordinate math: verbatim from the round-2/5 passing kernels ----
        const float depth = 1.0f / (base + (float)d * stepf);

        const float tx = k0 * depth + kt0;
        const float ty = k1 * depth + kt1;
        const float tz = k2 * depth + kt2;

        const float den = tz + 1e-6f;
        const float u = tx / den;
        const float v = ty / den;

        const float gx = (u - (float)(Wd / 2)) / (float)(Wd / 2);
        const float gy = (v - (float)(Hd / 2)) / (float)(Hd / 2);
        const float ix = (gx + 1.0f) * 0.5f * (float)(Wd - 1);
        const float iy = (gy + 1.0f) * 0.5f * (float)(Hd - 1);

        const float x0f = floorf(ix);
        const float y0f = floorf(iy);
        const float wx1 = ix - x0f;
        const float wy1 = iy - y0f;
        const float wx0 = 1.0f - wx1;
        const float wy0 = 1.0f - wy1;
        const float x1f = x0f + 1.0f;
        const float y1f = y0f + 1.0f;

        const float vx0 = (x0f >= 0.0f && x0f <= (float)(Wd - 1)) ? 1.0f : 0.0f;
        const float vx1 = (x1f >= 0.0f && x1f <= (float)(Wd - 1)) ? 1.0f : 0.0f;
        const float vy0 = (y0f >= 0.0f && y0f <= (float)(Hd - 1)) ? 1.0f : 0.0f;
        const float vy1 = (y1f >= 0.0f && y1f <= (float)(Hd - 1)) ? 1.0f : 0.0f;

        const float w00 = wx0 * wy0 * (vx0 * vy0);
        const float w10 = wx1 * wy0 * (vx1 * vy0);
        const float w01 = wx0 * wy1 * (vx0 * vy1);
        const float w11 = wx1 * wy1 * (vx1 * vy1);

        const int xi0 = (int)fminf(fmaxf(x0f, 0.0f), (float)(Wd - 1));
        const int xi1 = (int)fminf(fmaxf(x1f, 0.0f), (float)(Wd - 1));
        const int yi0 = (int)fminf(fmaxf(y0f, 0.0f), (float)(Hd - 1));
        const int yi1 = (int)fminf(fmaxf(y1f, 0.0f), (float)(Hd - 1));

        const int i00 = yi0 * Wd + xi0;
        const int i10 = yi0 * Wd + xi1;
        const int i01 = yi1 * Wd + xi0;
        const int i11 = yi1 * Wd + xi1;

        // weights as duplicated f16 pairs
        const __half2 w00p = __half2half2(__float2half_rn(w00));
        const __half2 w10p = __half2half2(__float2half_rn(w10));
        const __half2 w01p = __half2half2(__float2half_rn(w01));
        const __half2 w11p = __half2half2(__float2half_rn(w11));

        __half2 acc[4];
#pragma unroll
        for (int k = 0; k < 4; ++k) acc[k] = __half2half2(__float2half_rn(0.0f));

#pragma unroll
        for (int c = 0; c < Cd; ++c) {
            const uint4* rc = ws + (size_t)c * HWd;  // SGPR base
            const uint4 g00 = rc[i00];
            const uint4 g10 = rc[i10];
            const uint4 g01 = rc[i01];
            const uint4 g11 = rc[i11];

            const unsigned* u00 = (const unsigned*)&g00;
            const unsigned* u10 = (const unsigned*)&g10;
            const unsigned* u01 = (const unsigned*)&g01;
            const unsigned* u11 = (const unsigned*)&g11;
            const unsigned* ul  = (const unsigned*)&lv[c];

#pragma unroll
            for (int k = 0; k < 4; ++k) {
                const __half2 h00 = __builtin_bit_cast(__half2, u00[k]);
                const __half2 h10 = __builtin_bit_cast(__half2, u10[k]);
                const __half2 h01 = __builtin_bit_cast(__half2, u01[k]);
                const __half2 h11 = __builtin_bit_cast(__half2, u11[k]);
                const __half2 hl  = __builtin_bit_cast(__half2, ul[k]);
                __half2 wrp = __hfma2(w00p, h00,
                              __hfma2(w10p, h10,
                              __hfma2(w01p, h01,
                              __hmul2(w11p, h11))));
                const __half2 df = __habs2(__hsub2(wrp, hl));
                acc[k] = __hadd2(acc[k], df);
            }
        }

        // non-temporal stores: output is write-once, keep it out of L2 so the
        // 7.9 MB pack stays resident (round-2 FETCH=98MB >> 15.7MB compulsory)
        const int out_off = d * HWd + q;
#pragma unroll
        for (int k = 0; k < 4; ++k) {
            const float lo = __low2float(acc[k]);
            const float hi = __high2float(acc[k]);
            __builtin_nontemporal_store(lo, &out[(size_t)(2 * k) * (Dd * HWd) + out_off]);
            __builtin_nontemporal_store(hi, &out[(size_t)(2 * k + 1) * (Dd * HWd) + out_off]);
        }
    }
}

// ---------------- host-side geometry (pure f64, deterministic) ----------------

static void invert4(const double A[4][4], double inv[4][4]) {
    double M[4][8];
    for (int i = 0; i < 4; ++i) {
        for (int j = 0; j < 4; ++j) { M[i][j] = A[i][j]; M[i][j + 4] = (i == j) ? 1.0 : 0.0; }
    }
    for (int col = 0; col < 4; ++col) {
        int piv = col;
        for (int r = col + 1; r < 4; ++r)
            if (fabs(M[r][col]) > fabs(M[piv][col])) piv = r;
        if (piv != col)
            for (int j = 0; j < 8; ++j) { double t = M[col][j]; M[col][j] = M[piv][j]; M[piv][j] = t; }
        const double p = M[col][col];
        for (int j = 0; j < 8; ++j) M[col][j] /= p;
        for (int r = 0; r < 4; ++r) if (r != col) {
            const double f = M[r][col];
            for (int j = 0; j < 8; ++j) M[r][j] -= f * M[col][j];
        }
    }
    for (int i = 0; i < 4; ++i)
        for (int j = 0; j < 4; ++j) inv[i][j] = M[i][j + 4];
}

static void mul4(const double A[4][4], const double B[4][4], double C[4][4]) {
    for (int i = 0; i < 4; ++i)
        for (int j = 0; j < 4; ++j) {
            double s = 0.0;
            for (int k = 0; k < 4; ++k) s += A[i][k] * B[k][j];
            C[i][j] = s;
        }
}

static void mul3(const double A[3][3], const double B[3][3], double C[3][3]) {
    for (int i = 0; i < 3; ++i)
        for (int j = 0; j < 3; ++j) {
            double s = 0.0;
            for (int k = 0; k < 3; ++k) s += A[i][k] * B[k][j];
            C[i][j] = s;
        }
}

extern "C" void kernel_launch(void* const* d_in, const int* in_sizes, int n_in,
                              void* d_out, int out_size, void* d_ws, size_t ws_size,
                              hipStream_t stream) {
    const float* left  = (const float*)d_in[0];
    const float* right = (const float*)d_in[1];
    float* out = (float*)d_out;
    uint4* ws = (uint4*)d_ws;   // needs 6 * HW * 16 B = 7.86 MB

    const double LP[4][4] = {
        {0.07543147, 0.61393189, -0.78574661, 1.3405},
        {0.9970987, -0.03837025, 0.06574118, 0.6266},
        {0.01021131, -0.78842588, -0.61504501, 1.6575},
        {0.0, 0.0, 0.0, 1.0}};
    const double RP[4][4] = {
        {0.0640527011, 0.640832173, -0.765004168, 1.316},
        {0.997946496, -0.0409736058, 0.0492336713, 0.6254},
        {0.000205541383, -0.766586779, -0.642140692, 1.6196},
        {0.0, 0.0, 0.0, 1.0}};
    double K[3][3] = {{525.0, 0.0, 319.5}, {0.0, 525.0, 239.5}, {0.0, 0.0, 1.0}};
    for (int j = 0; j < 3; ++j) K[0][j] *= (double)Wd / 640.0;
    for (int j = 0; j < 3; ++j) K[1][j] *= (double)Hd / 480.0;

    double iRP[4][4];
    invert4(RP, iRP);
    double l2r[4][4];
    mul4(iRP, LP, l2r);

    double Rm[3][3], t[3];
    for (int i = 0; i < 3; ++i) {
        for (int j = 0; j < 3; ++j) Rm[i][j] = l2r[i][j];
        t[i] = l2r[i][3];
    }

    const double iK[3][3] = {
        {1.0 / K[0][0], 0.0, -K[0][2] / K[0][0]},
        {0.0, 1.0 / K[1][1], -K[1][2] / K[1][1]},
        {0.0, 0.0, 1.0}};

    double T1[3][3], KRKi[3][3];
    mul3(K, Rm, T1);
    mul3(T1, iK, KRKi);

    double Ktd[3] = {0.0, 0.0, 0.0};
    for (int i = 0; i < 3; ++i)
        for (int k = 0; k < 3; ++k) Ktd[i] += K[i][k] * t[k];
    const float kt0 = (float)Ktd[0], kt1 = (float)Ktd[1], kt2 = (float)Ktd[2];

    // 1) pack right + left -> [C][HW] x 8 f16 (batch-innermost)
    {
        dim3 grid(HWd / 256, 2 * Cd, 1);   // 320 x 6
        pack_f16<<<grid, dim3(256), 0, stream>>>(right, left, ws);
    }

    // 2) cost volume
    {
        dim3 grid(HWd / 256, Dd / DT, 1);   // 320 x 32
        costvol_kernel<<<grid, dim3(256), 0, stream>>>(
            ws, out,
            KRKi[0][0], KRKi[0][1], KRKi[0][2],
            KRKi[1][0], KRKi[1][1], KRKi[1][2],
            KRKi[2][0], KRKi[2][1], KRKi[2][2],
            kt0, kt1, kt2);
    }
}

// Round 8
// 56.235 us; speedup vs baseline: 2.9080x; 1.0103x over previous
//
#include <hip/hip_runtime.h>
#include <hip/hip_fp16.h>
#include <math.h>

#define Wd 320
#define Hd 256
#define Bd 8
#define Cd 3
#define Dd 64
#define HWd (Hd * Wd)   // 81920
#define DT 2            // depths per thread
#define SLAB_ROWS 32    // Hd / 8 XCDs
#define SLAB_PIX (SLAB_ROWS * Wd)       // 10240
#define SLAB_BLOCKS (SLAB_PIX / 256)    // 40

// ws layout: uint4 rpack[3][HW] (right), then uint4 lpack[3][HW] (left).
// Each uint4 = 8 f16 = batches 0..7 of one (c, pixel). Total 7.86 MB.

// ---- pack: [B][C][HW] f32 -> [C][HW] x (8 f16, batch-innermost), RNE ----
__global__ __launch_bounds__(256) void pack_f16(const float* __restrict__ right,
                                                const float* __restrict__ left,
                                                uint4* __restrict__ ws) {
    const int p = blockIdx.x * 256 + threadIdx.x;   // pixel in [0, HW)
    const int plane = blockIdx.y;                   // 0..5: 0-2 right c, 3-5 left c
    const int c = plane % Cd;
    const float* src = (plane < Cd ? right : left) + (size_t)c * HWd + p;
    unsigned w[4];
#pragma unroll
    for (int k = 0; k < 4; ++k) {
        const float f0 = src[(size_t)(2 * k) * (Cd * HWd)];
        const float f1 = src[(size_t)(2 * k + 1) * (Cd * HWd)];
        const __half2 h = __halves2half2(__float2half_rn(f0), __float2half_rn(f1));
        w[k] = __builtin_bit_cast(unsigned, h);
    }
    ws[(size_t)plane * HWd + p] = make_uint4(w[0], w[1], w[2], w[3]);
}

// ---- main: 1D grid, XCD-chunked: slab = bid%8 owns dst rows [slab*32, slab*32+32)
//      for ALL depths -> per-XCD L2 keeps the ~0.7MB source window resident.
__global__ __launch_bounds__(256) void costvol_kernel(
    const uint4* __restrict__ ws,     // rpack then lpack
    float* __restrict__ out,          // [B,D,H,W] f32
    double a00, double a01, double a02,
    double a10, double a11, double a12,
    double a20, double a21, double a22,
    float kt0, float kt1, float kt2)
{
    const int bid = blockIdx.x;
    const int slab = bid & 7;                // XCD chunk (HW dispatches bid%8 -> XCD)
    const int n = bid >> 3;
    const int dp = n / SLAB_BLOCKS;          // depth-pair index [0, 32)
    const int pb = n - dp * SLAB_BLOCKS;     // pixel-block within slab [0, 40)
    const int q = slab * SLAB_PIX + pb * 256 + (int)threadIdx.x;  // pixel id
    const int d0 = dp * DT;
    const int x = q % Wd;
    const int y = q / Wd;

    // hoisted across depths: f64 KRKi row (matches reference exactly)
    const float k0 = (float)(a00 * (double)x + a01 * (double)y + a02);
    const float k1 = (float)(a10 * (double)x + a11 * (double)y + a12);
    const float k2 = (float)(a20 * (double)x + a21 * (double)y + a22);

    // hoisted: packed left for this pixel (3 coalesced uint4 = 24 f16)
    uint4 lv[Cd];
#pragma unroll
    for (int c = 0; c < Cd; ++c) lv[c] = ws[(size_t)(Cd + c) * HWd + q];

    const float base  = (float)(1.0 / 50.0);
    const float stepf = (float)((1.0 / 0.5 - 1.0 / 50.0) / 63.0);

#pragma unroll
    for (int dd = 0; dd < DT; ++dd) {
        const int d = d0 + dd;

        // ---- coordinate math: verbatim from the round-2/5/6 passing kernels ----
        const float depth = 1.0f / (base + (float)d * stepf);

        const float tx = k0 * depth + kt0;
        const float ty = k1 * depth + kt1;
        const float tz = k2 * depth + kt2;

        const float den = tz + 1e-6f;
        const float u = tx / den;
        const float v = ty / den;

        const float gx = (u - (float)(Wd / 2)) / (float)(Wd / 2);
        const float gy = (v - (float)(Hd / 2)) / (float)(Hd / 2);
        const float ix = (gx + 1.0f) * 0.5f * (float)(Wd - 1);
        const float iy = (gy + 1.0f) * 0.5f * (float)(Hd - 1);

        const float x0f = floorf(ix);
        const float y0f = floorf(iy);
        const float wx1 = ix - x0f;
        const float wy1 = iy - y0f;
        const float wx0 = 1.0f - wx1;
        const float wy0 = 1.0f - wy1;
        const float x1f = x0f + 1.0f;
        const float y1f = y0f + 1.0f;

        const float vx0 = (x0f >= 0.0f && x0f <= (float)(Wd - 1)) ? 1.0f : 0.0f;
        const float vx1 = (x1f >= 0.0f && x1f <= (float)(Wd - 1)) ? 1.0f : 0.0f;
        const float vy0 = (y0f >= 0.0f && y0f <= (float)(Hd - 1)) ? 1.0f : 0.0f;
        const float vy1 = (y1f >= 0.0f && y1f <= (float)(Hd - 1)) ? 1.0f : 0.0f;

        const float w00 = wx0 * wy0 * (vx0 * vy0);
        const float w10 = wx1 * wy0 * (vx1 * vy0);
        const float w01 = wx0 * wy1 * (vx0 * vy1);
        const float w11 = wx1 * wy1 * (vx1 * vy1);

        const int xi0 = (int)fminf(fmaxf(x0f, 0.0f), (float)(Wd - 1));
        const int xi1 = (int)fminf(fmaxf(x1f, 0.0f), (float)(Wd - 1));
        const int yi0 = (int)fminf(fmaxf(y0f, 0.0f), (float)(Hd - 1));
        const int yi1 = (int)fminf(fmaxf(y1f, 0.0f), (float)(Hd - 1));

        const int i00 = yi0 * Wd + xi0;
        const int i10 = yi0 * Wd + xi1;
        const int i01 = yi1 * Wd + xi0;
        const int i11 = yi1 * Wd + xi1;

        // weights as duplicated f16 pairs
        const __half2 w00p = __half2half2(__float2half_rn(w00));
        const __half2 w10p = __half2half2(__float2half_rn(w10));
        const __half2 w01p = __half2half2(__float2half_rn(w01));
        const __half2 w11p = __half2half2(__float2half_rn(w11));

        __half2 acc[4];
#pragma unroll
        for (int k = 0; k < 4; ++k) acc[k] = __half2half2(__float2half_rn(0.0f));

#pragma unroll
        for (int c = 0; c < Cd; ++c) {
            const uint4* rc = ws + (size_t)c * HWd;  // SGPR base
            const uint4 g00 = rc[i00];
            const uint4 g10 = rc[i10];
            const uint4 g01 = rc[i01];
            const uint4 g11 = rc[i11];

            const unsigned* u00 = (const unsigned*)&g00;
            const unsigned* u10 = (const unsigned*)&g10;
            const unsigned* u01 = (const unsigned*)&g01;
            const unsigned* u11 = (const unsigned*)&g11;
            const unsigned* ul  = (const unsigned*)&lv[c];

#pragma unroll
            for (int k = 0; k < 4; ++k) {
                const __half2 h00 = __builtin_bit_cast(__half2, u00[k]);
                const __half2 h10 = __builtin_bit_cast(__half2, u10[k]);
                const __half2 h01 = __builtin_bit_cast(__half2, u01[k]);
                const __half2 h11 = __builtin_bit_cast(__half2, u11[k]);
                const __half2 hl  = __builtin_bit_cast(__half2, ul[k]);
                __half2 wrp = __hfma2(w00p, h00,
                              __hfma2(w10p, h10,
                              __hfma2(w01p, h01,
                              __hmul2(w11p, h11))));
                const __half2 df = __habs2(__hsub2(wrp, hl));
                acc[k] = __hadd2(acc[k], df);
            }
        }

        // non-temporal stores: write-once output, keep L2 for the pack
        const int out_off = d * HWd + q;
#pragma unroll
        for (int k = 0; k < 4; ++k) {
            const float lo = __low2float(acc[k]);
            const float hi = __high2float(acc[k]);
            __builtin_nontemporal_store(lo, &out[(size_t)(2 * k) * (Dd * HWd) + out_off]);
            __builtin_nontemporal_store(hi, &out[(size_t)(2 * k + 1) * (Dd * HWd) + out_off]);
        }
    }
}

// ---------------- host-side geometry (pure f64, deterministic) ----------------

static void invert4(const double A[4][4], double inv[4][4]) {
    double M[4][8];
    for (int i = 0; i < 4; ++i) {
        for (int j = 0; j < 4; ++j) { M[i][j] = A[i][j]; M[i][j + 4] = (i == j) ? 1.0 : 0.0; }
    }
    for (int col = 0; col < 4; ++col) {
        int piv = col;
        for (int r = col + 1; r < 4; ++r)
            if (fabs(M[r][col]) > fabs(M[piv][col])) piv = r;
        if (piv != col)
            for (int j = 0; j < 8; ++j) { double t = M[col][j]; M[col][j] = M[piv][j]; M[piv][j] = t; }
        const double p = M[col][col];
        for (int j = 0; j < 8; ++j) M[col][j] /= p;
        for (int r = 0; r < 4; ++r) if (r != col) {
            const double f = M[r][col];
            for (int j = 0; j < 8; ++j) M[r][j] -= f * M[col][j];
        }
    }
    for (int i = 0; i < 4; ++i)
        for (int j = 0; j < 4; ++j) inv[i][j] = M[i][j + 4];
}

static void mul4(const double A[4][4], const double B[4][4], double C[4][4]) {
    for (int i = 0; i < 4; ++i)
        for (int j = 0; j < 4; ++j) {
            double s = 0.0;
            for (int k = 0; k < 4; ++k) s += A[i][k] * B[k][j];
            C[i][j] = s;
        }
}

static void mul3(const double A[3][3], const double B[3][3], double C[3][3]) {
    for (int i = 0; i < 3; ++i)
        for (int j = 0; j < 3; ++j) {
            double s = 0.0;
            for (int k = 0; k < 3; ++k) s += A[i][k] * B[k][j];
            C[i][j] = s;
        }
}

extern "C" void kernel_launch(void* const* d_in, const int* in_sizes, int n_in,
                              void* d_out, int out_size, void* d_ws, size_t ws_size,
                              hipStream_t stream) {
    const float* left  = (const float*)d_in[0];
    const float* right = (const float*)d_in[1];
    float* out = (float*)d_out;
    uint4* ws = (uint4*)d_ws;   // needs 6 * HW * 16 B = 7.86 MB

    const double LP[4][4] = {
        {0.07543147, 0.61393189, -0.78574661, 1.3405},
        {0.9970987, -0.03837025, 0.06574118, 0.6266},
        {0.01021131, -0.78842588, -0.61504501, 1.6575},
        {0.0, 0.0, 0.0, 1.0}};
    const double RP[4][4] = {
        {0.0640527011, 0.640832173, -0.765004168, 1.316},
        {0.997946496, -0.0409736058, 0.0492336713, 0.6254},
        {0.000205541383, -0.766586779, -0.642140692, 1.6196},
        {0.0, 0.0, 0.0, 1.0}};
    double K[3][3] = {{525.0, 0.0, 319.5}, {0.0, 525.0, 239.5}, {0.0, 0.0, 1.0}};
    for (int j = 0; j < 3; ++j) K[0][j] *= (double)Wd / 640.0;
    for (int j = 0; j < 3; ++j) K[1][j] *= (double)Hd / 480.0;

    double iRP[4][4];
    invert4(RP, iRP);
    double l2r[4][4];
    mul4(iRP, LP, l2r);

    double Rm[3][3], t[3];
    for (int i = 0; i < 3; ++i) {
        for (int j = 0; j < 3; ++j) Rm[i][j] = l2r[i][j];
        t[i] = l2r[i][3];
    }

    const double iK[3][3] = {
        {1.0 / K[0][0], 0.0, -K[0][2] / K[0][0]},
        {0.0, 1.0 / K[1][1], -K[1][2] / K[1][1]},
        {0.0, 0.0, 1.0}};

    double T1[3][3], KRKi[3][3];
    mul3(K, Rm, T1);
    mul3(T1, iK, KRKi);

    double Ktd[3] = {0.0, 0.0, 0.0};
    for (int i = 0; i < 3; ++i)
        for (int k = 0; k < 3; ++k) Ktd[i] += K[i][k] * t[k];
    const float kt0 = (float)Ktd[0], kt1 = (float)Ktd[1], kt2 = (float)Ktd[2];

    // 1) pack right + left -> [C][HW] x 8 f16 (batch-innermost)
    {
        dim3 grid(HWd / 256, 2 * Cd, 1);   // 320 x 6
        pack_f16<<<grid, dim3(256), 0, stream>>>(right, left, ws);
    }

    // 2) cost volume: 1D grid, XCD-chunked (slab = bid%8)
    {
        dim3 grid(8 * SLAB_BLOCKS * (Dd / DT), 1, 1);   // 10240 blocks
        costvol_kernel<<<grid, dim3(256), 0, stream>>>(
            ws, out,
            KRKi[0][0], KRKi[0][1], KRKi[0][2],
            KRKi[1][0], KRKi[1][1], KRKi[1][2],
            KRKi[2][0], KRKi[2][1], KRKi[2][2],
            kt0, kt1, kt2);
    }
}